// Round 10
// baseline (5136.425 us; speedup 1.0000x reference)
//
#include <hip/hip_runtime.h>

#define L_DIM 1024
#define B_DIM 128
#define I_DIM 256
#define H_DIM 512

typedef unsigned short u16x8 __attribute__((ext_vector_type(8)));
typedef __bf16 bf16x8 __attribute__((ext_vector_type(8)));
typedef float f32x4 __attribute__((ext_vector_type(4)));
typedef unsigned long long u64;
typedef unsigned int u32;

static __device__ __forceinline__ unsigned short f2bf(float f) {
  unsigned u = __builtin_bit_cast(unsigned, f);
  u += 0x7FFFu + ((u >> 16) & 1u);
  return (unsigned short)(u >> 16);
}
static __device__ __forceinline__ float bf2f(unsigned short b) {
  return __builtin_bit_cast(float, ((unsigned)b) << 16);
}
static __device__ __forceinline__ bf16x8 ld_frag_g(const unsigned short* p, size_t idx8) {
  return __builtin_bit_cast(bf16x8, reinterpret_cast<const u16x8*>(p)[idx8]);
}

// ---------------------------------------------------------------------------
// Pack Wx and Wh into MFMA B-fragment order, split hi/lo bf16. (unchanged)
// NOTE: WxHi/WxLo region doubles as the rnn exchange slab; pack_weights
// rewriting it EVERY launch is what destroys stale stamps across graph
// replays (R6-proven). Do not reorder or skip.
// ---------------------------------------------------------------------------
__global__ void pack_weights(const float* __restrict__ Wx, const float* __restrict__ Wh,
                             unsigned short* __restrict__ WxHi, unsigned short* __restrict__ WxLo,
                             unsigned short* __restrict__ WhHi, unsigned short* __restrict__ WhLo) {
  int tid = blockIdx.x * blockDim.x + threadIdx.x;
  if (tid < 32 * 8 * 64) {
    int lane = tid & 63, kt = (tid >> 6) & 7, nt = tid >> 9;
    int n = nt * 16 + (lane & 15), k0 = kt * 32 + (lane >> 4) * 8;
    const float* src = Wx + (size_t)n * I_DIM + k0;
    #pragma unroll
    for (int j = 0; j < 8; ++j) {
      float v = src[j];
      unsigned short hb = f2bf(v);
      WxHi[(size_t)tid * 8 + j] = hb;
      WxLo[(size_t)tid * 8 + j] = f2bf(v - bf2f(hb));
    }
  }
  if (tid < 32 * 16 * 64) {
    int lane = tid & 63, kt = (tid >> 6) & 15, nt = tid >> 10;
    int n = nt * 16 + (lane & 15), k0 = kt * 32 + (lane >> 4) * 8;
    const float* src = Wh + (size_t)n * H_DIM + k0;
    #pragma unroll
    for (int j = 0; j < 8; ++j) {
      float v = src[j];
      unsigned short hb = f2bf(v);
      WhHi[(size_t)tid * 8 + j] = hb;
      WhLo[(size_t)tid * 8 + j] = f2bf(v - bf2f(hb));
    }
  }
}

// ---------------------------------------------------------------------------
// xproj (unchanged)
// ---------------------------------------------------------------------------
__global__ __launch_bounds__(256) void xproj_kernel(const float* __restrict__ x,
    const unsigned short* __restrict__ WxHi, const unsigned short* __restrict__ WxLo,
    const float* __restrict__ bh, float* __restrict__ out) {
  __shared__ unsigned short ahi[128][40];
  __shared__ unsigned short alo[128][40];
  const int tid = threadIdx.x, lane = tid & 63, wid = tid >> 6;
  const int mbase = blockIdx.x * 128, cbase = blockIdx.y * 128;
  const int wrow = (wid >> 1) * 64, wcol = (wid & 1) * 64;
  f32x4 acc[4][4] = {};
  const int srow = tid >> 1, shalf = (tid & 1) * 16;

  for (int kt = 0; kt < 8; ++kt) {
    const f32x4* src = reinterpret_cast<const f32x4*>(
        x + (size_t)(mbase + srow) * I_DIM + kt * 32 + shalf);
    f32x4 v[4];
    v[0] = src[0]; v[1] = src[1]; v[2] = src[2]; v[3] = src[3];
    u16x8 hh[2], ll[2];
    #pragma unroll
    for (int q = 0; q < 2; ++q) {
      #pragma unroll
      for (int e = 0; e < 8; ++e) {
        float f = v[q * 2 + (e >> 2)][e & 3];
        unsigned short hb = f2bf(f);
        hh[q][e] = hb;
        ll[q][e] = f2bf(f - bf2f(hb));
      }
    }
    __syncthreads();
    *reinterpret_cast<u16x8*>(&ahi[srow][shalf]) = hh[0];
    *reinterpret_cast<u16x8*>(&ahi[srow][shalf + 8]) = hh[1];
    *reinterpret_cast<u16x8*>(&alo[srow][shalf]) = ll[0];
    *reinterpret_cast<u16x8*>(&alo[srow][shalf + 8]) = ll[1];
    __syncthreads();

    bf16x8 amh[4], aml[4];
    #pragma unroll
    for (int m = 0; m < 4; ++m) {
      amh[m] = __builtin_bit_cast(bf16x8, *reinterpret_cast<const u16x8*>(
          &ahi[wrow + m * 16 + (lane & 15)][(lane >> 4) * 8]));
      aml[m] = __builtin_bit_cast(bf16x8, *reinterpret_cast<const u16x8*>(
          &alo[wrow + m * 16 + (lane & 15)][(lane >> 4) * 8]));
    }
    bf16x8 bhh[4], bll[4];
    #pragma unroll
    for (int n = 0; n < 4; ++n) {
      int ntg = (cbase + wcol) / 16 + n;
      size_t idx = (size_t)(ntg * 8 + kt) * 64 + lane;
      bhh[n] = ld_frag_g(WxHi, idx);
      bll[n] = ld_frag_g(WxLo, idx);
    }
    #pragma unroll
    for (int m = 0; m < 4; ++m) {
      #pragma unroll
      for (int n = 0; n < 4; ++n) {
        acc[m][n] = __builtin_amdgcn_mfma_f32_16x16x32_bf16(amh[m], bhh[n], acc[m][n], 0, 0, 0);
        acc[m][n] = __builtin_amdgcn_mfma_f32_16x16x32_bf16(aml[m], bhh[n], acc[m][n], 0, 0, 0);
        acc[m][n] = __builtin_amdgcn_mfma_f32_16x16x32_bf16(amh[m], bll[n], acc[m][n], 0, 0, 0);
      }
    }
  }

  #pragma unroll
  for (int n = 0; n < 4; ++n) {
    int col = cbase + wcol + n * 16 + (lane & 15);
    float bv = bh[col];
    #pragma unroll
    for (int m = 0; m < 4; ++m) {
      int rg = mbase + wrow + m * 16 + ((lane >> 4) << 2);
      #pragma unroll
      for (int r = 0; r < 4; ++r)
        out[(size_t)(rg + r) * H_DIM + col] = acc[m][n][r] + bv;
    }
  }
}

// ---------------------------------------------------------------------------
// Recurrence: 256 single-wave WGs. b -> g=b&7 (16 batch rows), cw=(b>>3)&31
// (16 output cols). Wh hi/lo fragments in VGPRs; no LDS, no barriers, no tags.
// Exchange = color-stamped slab [buf][g][16 rows][512 cols] of
// u32 = (step<<16)|bf16(h): a 4B store is atomic, so data+version land
// together. Producer fires 4 stamped agent stores and moves on (no ack).
// Consumer: issue out-stores + xp(t+2) prefetch, then BATCH-pull its 64 u64
// A-fragment words (relaxed agent loads, all independent), check all stamps,
// and re-pull the whole batch until fresh (each round = 1 parallel RTT).
// Liveness: forward-only dependence, retry-until-fresh (R6-proven).
// Buffer safety: wave publishes s+2 only after consuming s+1, which needs all
// of s+1 published, which needs all of s consumed -> step-s slot is dead
// before any s+2 overwrite. Replay safety: slab aliases WxHi/WxLo, which
// pack_weights rewrites every launch (stale stamps destroyed; bf16 weight
// bits never match stamps 1..1023 - only denormal/zero patterns would, and
// residuals are either 0x0000/0x8000 or normal-exponent values).
// ---------------------------------------------------------------------------
__global__ __launch_bounds__(64, 1) void rnn_kernel(const float* __restrict__ h0,
    const unsigned short* __restrict__ WhHi, const unsigned short* __restrict__ WhLo,
    u32* __restrict__ slab, float* __restrict__ out) {
  const int lane = threadIdx.x & 63;
  const int b = blockIdx.x;
  const int g = b & 7, cw = (b >> 3) & 31;

  // ---- one-time: Wh fragments -> VGPRs (16 cols x 512 k, hi+lo) ----
  bf16x8 wfh[16], wfl[16];
  #pragma unroll
  for (int kt = 0; kt < 16; ++kt) {
    size_t idx = (size_t)(cw * 16 + kt) * 64 + lane;
    wfh[kt] = ld_frag_g(WhHi, idx);
    wfl[kt] = ld_frag_g(WhLo, idx);
  }

  const int arow = lane & 15;        // A row (batch); D col within 16
  const int aoff = (lane >> 4) * 8;  // A k offset (elements)
  const int drow = (lane >> 4) * 4;  // D row base
  const int gcol = cw * 16 + (lane & 15);

  // ---- one-time: h_0 A-fragments from h0 (fp32 -> bf16) ----
  bf16x8 af[16];
  #pragma unroll
  for (int kt = 0; kt < 16; ++kt) {
    const f32x4* hp = reinterpret_cast<const f32x4*>(
        h0 + (size_t)(g * 16 + arow) * H_DIM + kt * 32 + aoff);
    f32x4 v0 = hp[0], v1 = hp[1];
    u16x8 hv;
    #pragma unroll
    for (int e = 0; e < 4; ++e) { hv[e] = f2bf(v0[e]); hv[4 + e] = f2bf(v1[e]); }
    af[kt] = __builtin_bit_cast(bf16x8, hv);
  }

  // ---- xp pipeline depth 2: xpA = xp(t), xpB = xp(t+1) ----
  f32x4 xpA, xpB;
  #pragma unroll
  for (int r = 0; r < 4; ++r)
    xpA[r] = out[(size_t)(g * 16 + drow + r) * H_DIM + gcol];
  #pragma unroll
  for (int r = 0; r < 4; ++r)
    xpB[r] = out[(size_t)B_DIM * H_DIM + (size_t)(g * 16 + drow + r) * H_DIM + gcol];

  for (int t = 0; t < L_DIM; ++t) {
    const size_t obase = ((size_t)t * B_DIM + g * 16) * H_DIM;

    // ---- z = h_t . Wh (hi+lo): 32 MFMAs, 4 chains ----
    f32x4 a0 = {}, a1 = {}, a2 = {}, a3 = {};
    #pragma unroll
    for (int kt = 0; kt < 16; kt += 2) {
      a0 = __builtin_amdgcn_mfma_f32_16x16x32_bf16(af[kt], wfh[kt], a0, 0, 0, 0);
      a1 = __builtin_amdgcn_mfma_f32_16x16x32_bf16(af[kt], wfl[kt], a1, 0, 0, 0);
      a2 = __builtin_amdgcn_mfma_f32_16x16x32_bf16(af[kt + 1], wfh[kt + 1], a2, 0, 0, 0);
      a3 = __builtin_amdgcn_mfma_f32_16x16x32_bf16(af[kt + 1], wfl[kt + 1], a3, 0, 0, 0);
    }

    float hv[4]; unsigned short hu[4];
    #pragma unroll
    for (int r = 0; r < 4; ++r) {
      float z = a0[r] + a1[r] + a2[r] + a3[r] + xpA[r];
      float e = __expf(2.0f * z);
      hv[r] = 1.0f - 2.0f / (e + 1.0f);  // tanh(z)
      hu[r] = f2bf(hv[r]);
    }

    if (t == L_DIM - 1) {
      #pragma unroll
      for (int r = 0; r < 4; ++r)
        out[obase + (size_t)(drow + r) * H_DIM + gcol] = hv[r];
      break;
    }

    const unsigned step = (unsigned)(t + 1);
    u32* sg = slab + (size_t)((step & 1) * 8 + g) * 8192;  // [16][512] u32
    const u32 cbits = step << 16;

    // ---- publish own 16x16 tile: 4 stamped u32 agent stores, no ack ----
    #pragma unroll
    for (int r = 0; r < 4; ++r)
      __hip_atomic_store(&sg[(drow + r) * 512 + gcol], cbits | (u32)hu[r],
                         __ATOMIC_RELAXED, __HIP_MEMORY_SCOPE_AGENT);

    // ---- off-critical-path: out stores + xp pipeline advance ----
    #pragma unroll
    for (int r = 0; r < 4; ++r)
      out[obase + (size_t)(drow + r) * H_DIM + gcol] = hv[r];
    xpA = xpB;
    {
      const int tn = (t + 2 < L_DIM) ? t + 2 : L_DIM - 1;
      const size_t obn = ((size_t)tn * B_DIM + g * 16) * H_DIM;
      #pragma unroll
      for (int r = 0; r < 4; ++r)
        xpB[r] = out[obn + (size_t)(drow + r) * H_DIM + gcol];
    }

    // ---- batched pull+poll: 64 u64 words = this lane's 16 A-fragments ----
    const u64* base = reinterpret_cast<const u64*>(sg) + arow * 256 + (lane >> 4) * 4;
    const u64 M = 0xFFFF0000FFFF0000ull;
    const u64 E = (u64)step * 0x0001000000010000ull;
    u64 pv[64];
    bool ok;
    do {
      #pragma unroll
      for (int kt = 0; kt < 16; ++kt) {
        #pragma unroll
        for (int j = 0; j < 4; ++j)
          pv[kt * 4 + j] = __hip_atomic_load(base + kt * 16 + j,
                                             __ATOMIC_RELAXED, __HIP_MEMORY_SCOPE_AGENT);
      }
      ok = true;
      #pragma unroll
      for (int i = 0; i < 64; ++i) ok = ok && ((pv[i] & M) == E);
    } while (!ok);

    // ---- strip stamps -> A-fragments ----
    #pragma unroll
    for (int kt = 0; kt < 16; ++kt) {
      u16x8 w;
      #pragma unroll
      for (int j = 0; j < 4; ++j) {
        u64 q = pv[kt * 4 + j];
        w[2 * j] = (unsigned short)q;
        w[2 * j + 1] = (unsigned short)(q >> 32);
      }
      af[kt] = __builtin_bit_cast(bf16x8, w);
    }
  }
}

extern "C" void kernel_launch(void* const* d_in, const int* in_sizes, int n_in,
                              void* d_out, int out_size, void* d_ws, size_t ws_size,
                              hipStream_t stream) {
  (void)in_sizes; (void)n_in; (void)out_size; (void)ws_size;
  const float* x  = (const float*)d_in[0];
  const float* h0 = (const float*)d_in[1];
  const float* Wx = (const float*)d_in[2];
  const float* Wh = (const float*)d_in[3];
  const float* bh = (const float*)d_in[4];
  float* out = (float*)d_out;

  unsigned short* WxHi = (unsigned short*)d_ws;       // 131072 u16 (dead after xproj)
  unsigned short* WxLo = WxHi + 131072;               // 131072 u16 (dead after xproj)
  unsigned short* WhHi = WxLo + 131072;               // 262144 u16
  unsigned short* WhLo = WhHi + 262144;               // 262144 u16 (ends 1572864 B)
  // Exchange slab [2][8][16][512] u32 = 524288 B, aliasing WxHi+WxLo exactly.
  // pack_weights rewrites this region every launch -> stale stamps destroyed.
  u32* slab = (u32*)d_ws;

  hipLaunchKernelGGL(pack_weights, dim3(128), dim3(256), 0, stream,
                     Wx, Wh, WxHi, WxLo, WhHi, WhLo);
  hipLaunchKernelGGL(xproj_kernel, dim3(1024, 4), dim3(256), 0, stream,
                     x, WxHi, WxLo, bh, out);
  hipLaunchKernelGGL(rnn_kernel, dim3(256), dim3(64), 0, stream,
                     h0, WhHi, WhLo, slab, out);
}

// Round 11
// 3260.641 us; speedup vs baseline: 1.5753x; 1.5753x over previous
//
#include <hip/hip_runtime.h>

#define L_DIM 1024
#define B_DIM 128
#define I_DIM 256
#define H_DIM 512

typedef unsigned short u16x8 __attribute__((ext_vector_type(8)));
typedef __bf16 bf16x8 __attribute__((ext_vector_type(8)));
typedef float f32x4 __attribute__((ext_vector_type(4)));
typedef unsigned long long u64;
typedef unsigned int u32;
typedef u64 u64x2 __attribute__((ext_vector_type(2)));

static __device__ __forceinline__ unsigned short f2bf(float f) {
  unsigned u = __builtin_bit_cast(unsigned, f);
  u += 0x7FFFu + ((u >> 16) & 1u);
  return (unsigned short)(u >> 16);
}
static __device__ __forceinline__ float bf2f(unsigned short b) {
  return __builtin_bit_cast(float, ((unsigned)b) << 16);
}
static __device__ __forceinline__ bf16x8 ld_frag_g(const unsigned short* p, size_t idx8) {
  return __builtin_bit_cast(bf16x8, reinterpret_cast<const u16x8*>(p)[idx8]);
}

// ---------------------------------------------------------------------------
// Pack Wx and Wh into MFMA B-fragment order, split hi/lo bf16. (unchanged)
// ---------------------------------------------------------------------------
__global__ void pack_weights(const float* __restrict__ Wx, const float* __restrict__ Wh,
                             unsigned short* __restrict__ WxHi, unsigned short* __restrict__ WxLo,
                             unsigned short* __restrict__ WhHi, unsigned short* __restrict__ WhLo) {
  int tid = blockIdx.x * blockDim.x + threadIdx.x;
  if (tid < 32 * 8 * 64) {
    int lane = tid & 63, kt = (tid >> 6) & 7, nt = tid >> 9;
    int n = nt * 16 + (lane & 15), k0 = kt * 32 + (lane >> 4) * 8;
    const float* src = Wx + (size_t)n * I_DIM + k0;
    #pragma unroll
    for (int j = 0; j < 8; ++j) {
      float v = src[j];
      unsigned short hb = f2bf(v);
      WxHi[(size_t)tid * 8 + j] = hb;
      WxLo[(size_t)tid * 8 + j] = f2bf(v - bf2f(hb));
    }
  }
  if (tid < 32 * 16 * 64) {
    int lane = tid & 63, kt = (tid >> 6) & 15, nt = tid >> 10;
    int n = nt * 16 + (lane & 15), k0 = kt * 32 + (lane >> 4) * 8;
    const float* src = Wh + (size_t)n * H_DIM + k0;
    #pragma unroll
    for (int j = 0; j < 8; ++j) {
      float v = src[j];
      unsigned short hb = f2bf(v);
      WhHi[(size_t)tid * 8 + j] = hb;
      WhLo[(size_t)tid * 8 + j] = f2bf(v - bf2f(hb));
    }
  }
}

// ---------------------------------------------------------------------------
// xproj (unchanged)
// ---------------------------------------------------------------------------
__global__ __launch_bounds__(256) void xproj_kernel(const float* __restrict__ x,
    const unsigned short* __restrict__ WxHi, const unsigned short* __restrict__ WxLo,
    const float* __restrict__ bh, float* __restrict__ out) {
  __shared__ unsigned short ahi[128][40];
  __shared__ unsigned short alo[128][40];
  const int tid = threadIdx.x, lane = tid & 63, wid = tid >> 6;
  const int mbase = blockIdx.x * 128, cbase = blockIdx.y * 128;
  const int wrow = (wid >> 1) * 64, wcol = (wid & 1) * 64;
  f32x4 acc[4][4] = {};
  const int srow = tid >> 1, shalf = (tid & 1) * 16;

  for (int kt = 0; kt < 8; ++kt) {
    const f32x4* src = reinterpret_cast<const f32x4*>(
        x + (size_t)(mbase + srow) * I_DIM + kt * 32 + shalf);
    f32x4 v[4];
    v[0] = src[0]; v[1] = src[1]; v[2] = src[2]; v[3] = src[3];
    u16x8 hh[2], ll[2];
    #pragma unroll
    for (int q = 0; q < 2; ++q) {
      #pragma unroll
      for (int e = 0; e < 8; ++e) {
        float f = v[q * 2 + (e >> 2)][e & 3];
        unsigned short hb = f2bf(f);
        hh[q][e] = hb;
        ll[q][e] = f2bf(f - bf2f(hb));
      }
    }
    __syncthreads();
    *reinterpret_cast<u16x8*>(&ahi[srow][shalf]) = hh[0];
    *reinterpret_cast<u16x8*>(&ahi[srow][shalf + 8]) = hh[1];
    *reinterpret_cast<u16x8*>(&alo[srow][shalf]) = ll[0];
    *reinterpret_cast<u16x8*>(&alo[srow][shalf + 8]) = ll[1];
    __syncthreads();

    bf16x8 amh[4], aml[4];
    #pragma unroll
    for (int m = 0; m < 4; ++m) {
      amh[m] = __builtin_bit_cast(bf16x8, *reinterpret_cast<const u16x8*>(
          &ahi[wrow + m * 16 + (lane & 15)][(lane >> 4) * 8]));
      aml[m] = __builtin_bit_cast(bf16x8, *reinterpret_cast<const u16x8*>(
          &alo[wrow + m * 16 + (lane & 15)][(lane >> 4) * 8]));
    }
    bf16x8 bhh[4], bll[4];
    #pragma unroll
    for (int n = 0; n < 4; ++n) {
      int ntg = (cbase + wcol) / 16 + n;
      size_t idx = (size_t)(ntg * 8 + kt) * 64 + lane;
      bhh[n] = ld_frag_g(WxHi, idx);
      bll[n] = ld_frag_g(WxLo, idx);
    }
    #pragma unroll
    for (int m = 0; m < 4; ++m) {
      #pragma unroll
      for (int n = 0; n < 4; ++n) {
        acc[m][n] = __builtin_amdgcn_mfma_f32_16x16x32_bf16(amh[m], bhh[n], acc[m][n], 0, 0, 0);
        acc[m][n] = __builtin_amdgcn_mfma_f32_16x16x32_bf16(aml[m], bhh[n], acc[m][n], 0, 0, 0);
        acc[m][n] = __builtin_amdgcn_mfma_f32_16x16x32_bf16(amh[m], bll[n], acc[m][n], 0, 0, 0);
      }
    }
  }

  #pragma unroll
  for (int n = 0; n < 4; ++n) {
    int col = cbase + wcol + n * 16 + (lane & 15);
    float bv = bh[col];
    #pragma unroll
    for (int m = 0; m < 4; ++m) {
      int rg = mbase + wrow + m * 16 + ((lane >> 4) << 2);
      #pragma unroll
      for (int r = 0; r < 4; ++r)
        out[(size_t)(rg + r) * H_DIM + col] = acc[m][n][r] + bv;
    }
  }
}

// ---------------------------------------------------------------------------
// Recurrence: 256 single-wave WGs. b -> g=b&7 (16 batch rows), cw=(b>>3)&31
// (16 output cols). Wh hi/lo fragments in VGPRs; no LDS, no barriers.
// Exchange protocol (relaxed AGENT primitives only, R7-proven class):
//   producer: 4 bf16 agent stores -> wave vmcnt(0) ack -> lane0
//             fetch_add(+1) on the single (buf,g) arrive-counter.
//   consumer: out stores + xp(t+2) prefetch fly; then ALL lanes poll the ONE
//             counter word (coalesced same-address load, no cross-lane skew)
//             for the monotonic target 32*ceil(step/2); then pull its 16
//             A-fragments once (fresh by increment-after-ack ordering).
// Monotonic counter => no reset hazard; memset each launch => replay-safe.
// ---------------------------------------------------------------------------
__global__ __launch_bounds__(64, 1) void rnn_kernel(const float* __restrict__ h0,
    const unsigned short* __restrict__ WhHi, const unsigned short* __restrict__ WhLo,
    u32* __restrict__ ctr, unsigned short* __restrict__ slab,
    float* __restrict__ out) {
  const int lane = threadIdx.x & 63;
  const int b = blockIdx.x;
  const int g = b & 7, cw = (b >> 3) & 31;

  // ---- one-time: Wh fragments -> VGPRs (16 cols x 512 k, hi+lo) ----
  bf16x8 wfh[16], wfl[16];
  #pragma unroll
  for (int kt = 0; kt < 16; ++kt) {
    size_t idx = (size_t)(cw * 16 + kt) * 64 + lane;
    wfh[kt] = ld_frag_g(WhHi, idx);
    wfl[kt] = ld_frag_g(WhLo, idx);
  }

  const int arow = lane & 15;        // A row (batch); D col within 16
  const int aoff = (lane >> 4) * 8;  // A k offset (elements)
  const int drow = (lane >> 4) * 4;  // D row base
  const int gcol = cw * 16 + (lane & 15);

  // ---- one-time: h_0 A-fragments from h0 (fp32 -> bf16) ----
  bf16x8 af[16];
  #pragma unroll
  for (int kt = 0; kt < 16; ++kt) {
    const f32x4* hp = reinterpret_cast<const f32x4*>(
        h0 + (size_t)(g * 16 + arow) * H_DIM + kt * 32 + aoff);
    f32x4 v0 = hp[0], v1 = hp[1];
    u16x8 hv;
    #pragma unroll
    for (int e = 0; e < 4; ++e) { hv[e] = f2bf(v0[e]); hv[4 + e] = f2bf(v1[e]); }
    af[kt] = __builtin_bit_cast(bf16x8, hv);
  }

  // ---- xp pipeline depth 2: xpA = xp(t), xpB = xp(t+1) in flight ----
  f32x4 xpA, xpB;
  #pragma unroll
  for (int r = 0; r < 4; ++r)
    xpA[r] = out[(size_t)(g * 16 + drow + r) * H_DIM + gcol];
  #pragma unroll
  for (int r = 0; r < 4; ++r)
    xpB[r] = out[(size_t)B_DIM * H_DIM + (size_t)(g * 16 + drow + r) * H_DIM + gcol];

  for (int t = 0; t < L_DIM; ++t) {
    const size_t obase = ((size_t)t * B_DIM + g * 16) * H_DIM;

    // ---- z = h_t . Wh (hi+lo): 32 MFMAs, 4 chains ----
    f32x4 a0 = {}, a1 = {}, a2 = {}, a3 = {};
    #pragma unroll
    for (int kt = 0; kt < 16; kt += 2) {
      a0 = __builtin_amdgcn_mfma_f32_16x16x32_bf16(af[kt], wfh[kt], a0, 0, 0, 0);
      a1 = __builtin_amdgcn_mfma_f32_16x16x32_bf16(af[kt], wfl[kt], a1, 0, 0, 0);
      a2 = __builtin_amdgcn_mfma_f32_16x16x32_bf16(af[kt + 1], wfh[kt + 1], a2, 0, 0, 0);
      a3 = __builtin_amdgcn_mfma_f32_16x16x32_bf16(af[kt + 1], wfl[kt + 1], a3, 0, 0, 0);
    }

    float hv[4]; unsigned short hu[4];
    #pragma unroll
    for (int r = 0; r < 4; ++r) {
      float z = a0[r] + a1[r] + a2[r] + a3[r] + xpA[r];
      float e = __expf(2.0f * z);
      hv[r] = 1.0f - 2.0f / (e + 1.0f);  // tanh(z)
      hu[r] = f2bf(hv[r]);
    }

    if (t == L_DIM - 1) {
      #pragma unroll
      for (int r = 0; r < 4; ++r)
        out[obase + (size_t)(drow + r) * H_DIM + gcol] = hv[r];
      break;
    }

    const unsigned step = (unsigned)(t + 1);
    const unsigned buf = step & 1;
    unsigned short* sg = slab + (size_t)(buf * 8 + g) * 8192;  // [16][512] bf16
    u32* cp = ctr + (size_t)(buf * 8 + g) * 16;                // 64B-strided counter

    // ---- publish own tile: 4x 2B agent stores ----
    #pragma unroll
    for (int r = 0; r < 4; ++r)
      __hip_atomic_store(&sg[(drow + r) * H_DIM + gcol], hu[r],
                         __ATOMIC_RELAXED, __HIP_MEMORY_SCOPE_AGENT);
    __builtin_amdgcn_sched_barrier(0);
    asm volatile("s_waitcnt vmcnt(0)" ::: "memory");  // tile at coherent point
    __builtin_amdgcn_sched_barrier(0);
    if (lane == 0)
      __hip_atomic_fetch_add(cp, 1u, __ATOMIC_RELAXED, __HIP_MEMORY_SCOPE_AGENT);

    // ---- off-critical-path: out stores + xp pipeline advance ----
    #pragma unroll
    for (int r = 0; r < 4; ++r)
      out[obase + (size_t)(drow + r) * H_DIM + gcol] = hv[r];
    xpA = xpB;
    {
      const int tn = (t + 2 < L_DIM) ? t + 2 : L_DIM - 1;
      const size_t obn = ((size_t)tn * B_DIM + g * 16) * H_DIM;
      #pragma unroll
      for (int r = 0; r < 4; ++r)
        xpB[r] = out[obn + (size_t)(drow + r) * H_DIM + gcol];
    }

    // ---- poll the single arrive-counter (monotonic target, all lanes) ----
    const u32 target = 32u * ((step + 1) >> 1);
    while (__hip_atomic_load(cp, __ATOMIC_RELAXED, __HIP_MEMORY_SCOPE_AGENT) < target) {}
    __builtin_amdgcn_sched_barrier(0);
    asm volatile("" ::: "memory");

    // ---- pull h_{t+1} A-fragments once (2 u64 agent loads per ktile) ----
    const u64* sp = reinterpret_cast<const u64*>(sg);
    #pragma unroll
    for (int kt = 0; kt < 16; ++kt) {
      const u64* p = sp + arow * 128 + kt * 8 + (lane >> 4) * 2;
      u64x2 pv2;
      pv2[0] = __hip_atomic_load(p, __ATOMIC_RELAXED, __HIP_MEMORY_SCOPE_AGENT);
      pv2[1] = __hip_atomic_load(p + 1, __ATOMIC_RELAXED, __HIP_MEMORY_SCOPE_AGENT);
      af[kt] = __builtin_bit_cast(bf16x8, pv2);
    }
  }
}

extern "C" void kernel_launch(void* const* d_in, const int* in_sizes, int n_in,
                              void* d_out, int out_size, void* d_ws, size_t ws_size,
                              hipStream_t stream) {
  (void)in_sizes; (void)n_in; (void)out_size; (void)ws_size;
  const float* x  = (const float*)d_in[0];
  const float* h0 = (const float*)d_in[1];
  const float* Wx = (const float*)d_in[2];
  const float* Wh = (const float*)d_in[3];
  const float* bh = (const float*)d_in[4];
  float* out = (float*)d_out;

  unsigned short* WxHi = (unsigned short*)d_ws;       // 131072 u16
  unsigned short* WxLo = WxHi + 131072;               // 131072 u16
  unsigned short* WhHi = WxLo + 131072;               // 262144 u16
  unsigned short* WhLo = WhHi + 262144;               // 262144 u16 (ends 1572864 B)
  unsigned short* slab = (unsigned short*)((char*)d_ws + 1572864);  // [2][8][16][512] bf16 = 262144 B
  u32*            ctr  = (u32*)((char*)d_ws + 1835008);             // 16 counters x 64B = 1024 B

  // per-launch: zero arrive-counters (deterministic under graph replay)
  hipMemsetAsync(ctr, 0, 1024, stream);

  hipLaunchKernelGGL(pack_weights, dim3(128), dim3(256), 0, stream,
                     Wx, Wh, WxHi, WxLo, WhHi, WhLo);
  hipLaunchKernelGGL(xproj_kernel, dim3(1024, 4), dim3(256), 0, stream,
                     x, WxHi, WxLo, bh, out);
  hipLaunchKernelGGL(rnn_kernel, dim3(256), dim3(64), 0, stream,
                     h0, WhHi, WhLo, ctr, slab, out);
}